// Round 3
// baseline (226.040 us; speedup 1.0000x reference)
//
#include <hip/hip_runtime.h>
#include <hip/hip_bf16.h>

// Problem constants
#define NB   32
#define NT   128
#define NC   64
#define NF   64
#define NK   128
#define NCP  62            // NC - NKH + 1
#define BN_EPS 1e-3f

typedef __attribute__((ext_vector_type(8))) short short8;
typedef __attribute__((ext_vector_type(4))) float floatx4;

__device__ __forceinline__ short f2bf(float f) {
    __hip_bfloat16 h = __float2bfloat16(f);
    return *reinterpret_cast<short*>(&h);
}

// Prep: B fragments in exact wave-load order.
// bfrag[(nt*6+s)*64 + lane], lane=(q<<4)|col holds 8 bf16 of w[j][n],
// j = s*32 + q*8 .. +7, n = nt*16 + col.  (3072 chunks = 48 KB)
__global__ __launch_bounds__(256) void build_bfrag(
    const float* __restrict__ w, short8* __restrict__ bfrag)
{
    int idx  = blockIdx.x * 256 + threadIdx.x;   // 0..3071
    int lane = idx & 63;
    int ts   = idx >> 6;                         // nt*6 + s
    int nt   = ts / 6;
    int s    = ts - nt * 6;
    int col  = lane & 15, q = lane >> 4;
    int n    = nt * 16 + col;
    int j0   = s * 32 + q * 8;
    short8 p;
    #pragma unroll
    for (int e = 0; e < 8; ++e) p[e] = f2bf(w[(size_t)(j0 + e) * NK + n]);
    bfrag[idx] = p;
}

// LDS-free MFMA kernel: block = one bt slice; wave wv = rows 16wv..16wv+15.
__global__ __launch_bounds__(256, 4) void tccnn_mfma2(
    const float* __restrict__ x, const short8* __restrict__ bfrag,
    const float* __restrict__ bias, const float* __restrict__ gamma,
    const float* __restrict__ beta, const float* __restrict__ mean,
    const float* __restrict__ var, float* __restrict__ out)
{
    const int bt   = blockIdx.x;
    const int tid  = threadIdx.x;
    const int wv   = tid >> 6;
    const int lane = tid & 63;
    const int col  = lane & 15;
    const int q    = lane >> 4;
    const int t    = bt & (NT - 1);
    const int row  = wv * 16 + col;              // cp index, 0..63

    // ---- A fragments: direct global f32 loads + register bf16 convert ----
    const float4* xg = (const float4*)x;
    const long maxi  = (long)NB * NT * 1024 - 2; // clamp (rows 62/63 tail OOB)
    long base4 = (long)bt * 1024 + row * 16 + q * 2;
    short8 afrag[6];
    #pragma unroll
    for (int s = 0; s < 6; ++s) {
        long i0 = base4 + s * 8;
        i0 = i0 > maxi ? maxi : i0;
        float4 v0 = xg[i0];
        float4 v1 = xg[i0 + 1];
        short8 p;
        p[0] = f2bf(v0.x); p[1] = f2bf(v0.y); p[2] = f2bf(v0.z); p[3] = f2bf(v0.w);
        p[4] = f2bf(v1.x); p[5] = f2bf(v1.y); p[6] = f2bf(v1.z); p[7] = f2bf(v1.w);
        afrag[s] = p;
    }

    floatx4 acc[8];
    #pragma unroll
    for (int nt = 0; nt < 8; ++nt) acc[nt] = (floatx4){0.f, 0.f, 0.f, 0.f};

    // ---- main loop: A held in regs, B streamed coalesced from L1/L2 ----
    #pragma unroll
    for (int nt = 0; nt < 8; ++nt) {
        short8 b[6];
        #pragma unroll
        for (int s = 0; s < 6; ++s) b[s] = bfrag[(nt * 6 + s) * 64 + lane];
        #pragma unroll
        for (int s = 0; s < 6; ++s)
            acc[nt] = __builtin_amdgcn_mfma_f32_16x16x32_bf16(afrag[s], b[s], acc[nt], 0, 0, 0);
    }

    // ---- epilogue: bias + BN + relu ----
    const float scale = gamma[t] * rsqrtf(var[t] + BN_EPS);
    const float shift = beta[t] - mean[t] * scale;

    float* obase = out + (size_t)bt * (NCP * NK);
    #pragma unroll
    for (int nt = 0; nt < 8; ++nt) {
        const int k  = nt * 16 + col;
        const float bv = bias[k];
        #pragma unroll
        for (int reg = 0; reg < 4; ++reg) {
            const int cp = wv * 16 + q * 4 + reg;
            if (cp < NCP) {
                float v = (acc[nt][reg] + bv) * scale + shift;
                obase[(size_t)cp * NK + k] = v > 0.f ? v : 0.f;
            }
        }
    }
}

extern "C" void kernel_launch(void* const* d_in, const int* in_sizes, int n_in,
                              void* d_out, int out_size, void* d_ws, size_t ws_size,
                              hipStream_t stream) {
    const float* x     = (const float*)d_in[0];
    const float* w     = (const float*)d_in[1];
    const float* bias  = (const float*)d_in[2];
    const float* gamma = (const float*)d_in[3];
    const float* beta  = (const float*)d_in[4];
    const float* mean  = (const float*)d_in[5];
    const float* var   = (const float*)d_in[6];
    float* out = (float*)d_out;
    short8* bfrag = (short8*)d_ws;               // 48 KB scratch

    build_bfrag<<<dim3(12), dim3(256), 0, stream>>>(w, bfrag);
    tccnn_mfma2<<<dim3(NB * NT), dim3(256), 0, stream>>>(
        x, bfrag, bias, gamma, beta, mean, var, out);
}